// Round 5
// baseline (2318.647 us; speedup 1.0000x reference)
//
#include <hip/hip_runtime.h>

// Net_23484881175023: conv1d(k=3,stride=3) -> LSTM(input=1, hidden=10, T=8192) -> Linear(10,3)
// B=512, L=24576, Lp=8192.
//
// Round-5: TLP instead of ILP. Round-4 proved the wave's issue stream is
// ~88% occupied (2 chains in 1 wave = 2x time), so intra-wave interleaving
// can't win. But a SIMD can issue a DIFFERENT resident wave during one wave's
// hazard s_nops / dependency stalls. All previous configs ran 1 wave per
// active SIMD. This round: 32 blocks x 1024 threads = 16 waves/block =
// 4 waves/SIMD on 32 CUs. Kernel body identical to round 3 (734 us).
// time/step = max(C/4, V_pure); measured dur directly yields V_pure.
//
// Per-step math (per batch): h-dot via packed f16 dot2 (4 readlanes of packed
// pairs + f32 head), unified sigmoid activation with smul folded into weights,
// pre-scaled cell state cs = -2*log2e*c, quad DPP gathers for i/f/g/o.

#define DEV __device__ __forceinline__

typedef _Float16 half2v __attribute__((ext_vector_type(2)));

DEV float rl_f(float v, int lane) {
  return __int_as_float(__builtin_amdgcn_readlane(__float_as_int(v), lane));
}

DEV half2v rl_h2(half2v v, int lane) {
  int i = __builtin_amdgcn_readlane(__builtin_bit_cast(int, v), lane);
  return __builtin_bit_cast(half2v, i);
}

DEV half2v pkrtz(float a, float b) {
  return __builtin_bit_cast(half2v, __builtin_amdgcn_cvt_pkrtz(a, b));
}

template <int CTRL>
DEV float dpp_f(float v) {
#if __has_builtin(__builtin_amdgcn_mov_dpp)
  return __int_as_float(__builtin_amdgcn_mov_dpp(__float_as_int(v), CTRL, 0xF, 0xF, true));
#else
  return __int_as_float(__builtin_amdgcn_update_dpp(0, __float_as_int(v), CTRL, 0xF, 0xF, true));
#endif
}

DEV float fast_exp2(float x) {
#if __has_builtin(__builtin_amdgcn_exp2f)
  return __builtin_amdgcn_exp2f(x);
#else
  return __exp2f(x);
#endif
}

DEV float fast_rcp(float x) { return __builtin_amdgcn_rcpf(x); }

#if __has_builtin(__builtin_amdgcn_fdot2)
#define USE_FDOT2 1
#else
#define USE_FDOT2 0
#endif

constexpr int kB = 512;
constexpr int kL = 24576;
constexpr int kLp = 8192;      // kL / 3
constexpr int kHid = 10;
constexpr int kChunk = 64;     // timesteps per chunk (one ct per lane)
constexpr int kNChunk = kLp / kChunk;  // 128
constexpr int kWavesPerBlock = 16;     // 4 waves per SIMD

__global__ __launch_bounds__(1024, 1) void lstm_fused(
    const float* __restrict__ x,       // (B, L, 1)
    const float* __restrict__ conv_w,  // (1,1,3)
    const float* __restrict__ conv_b,  // (1,)
    const float* __restrict__ w_ih,    // (40,1)
    const float* __restrict__ w_hh,    // (40,10)
    const float* __restrict__ b_ih,    // (40,)
    const float* __restrict__ b_hh,    // (40,)
    const float* __restrict__ mlp_w,   // (3,10)
    const float* __restrict__ mlp_b,   // (3,)
    float* __restrict__ out) {         // (B,3)
  const int lane = threadIdx.x & 63;
  const int wave = threadIdx.x >> 6;
  const int b = blockIdx.x * kWavesPerBlock + wave;

  const int hid = lane >> 2;   // 0..9 for active lanes
  const int gt = lane & 3;     // 0:i 1:f 2:g 3:o (torch gate order)
  const bool active = (lane < 40);
  const int r = active ? (gt * kHid + hid) : 0;  // row in the 4H-stacked weights

  // uniform conv params (scalar loads)
  const float cw0 = conv_w[0], cw1 = conv_w[1], cw2 = conv_w[2];
  const float cbv = conv_b[0];

  constexpr float kL2E = 1.4426950408889634f;  // log2(e)
  // gate g uses sigmoid(2x) (tanh folding); i/f/o use sigmoid(x).
  // Fold the exp2 scale into the weights so the dot feeds exp2 directly.
  const float smul = (gt == 2) ? (-2.0f * kL2E) : (-kL2E);

  const float wih = w_ih[r] * smul;
  const float bsum = (b_ih[r] + b_hh[r]) * smul;
  const float* wr = w_hh + r * kHid;
  const float w0s = wr[0] * smul, w1s = wr[1] * smul;
  const float w2s = wr[2] * smul, w3s = wr[3] * smul, w4s = wr[4] * smul;
  const float w5s = wr[5] * smul, w6s = wr[6] * smul, w7s = wr[7] * smul;
  const float w8s = wr[8] * smul, w9s = wr[9] * smul;

#if USE_FDOT2
  const half2v wp1 = pkrtz(w2s, w3s);
  const half2v wp2 = pkrtz(w4s, w5s);
  const half2v wp3 = pkrtz(w6s, w7s);
  const half2v wp4 = pkrtz(w8s, w9s);
#endif

  // cell-update constants (cs = -2*log2e * c is the tracked state):
  //   cs_new = f*cs + C2*i + C4*i*g,  C4 = -4*log2e, C2 = 2*log2e
  const float C4 = -4.0f * kL2E;
  const float C2 = 2.0f * kL2E;

  const float* xb = x + (size_t)b * kL;
  const int xoff = lane * 3;

  // prefetch chunk 0's x values
  float x0 = xb[xoff + 0];
  float x1 = xb[xoff + 1];
  float x2 = xb[xoff + 2];

  float h = 0.0f;   // lane's quad value of h[hid]
  float cs = 0.0f;  // -2*log2e * c[hid]

  for (int ch = 0; ch < kNChunk; ++ch) {
    // conv output for timestep (ch*64 + lane), all 64 lanes
    float ct = fmaf(x2, cw2, fmaf(x1, cw1, fmaf(x0, cw0, cbv)));
    ct = fmaxf(ct, 0.0f);

    // prefetch next chunk (consumed after the 64-step inner loop)
    if (ch + 1 < kNChunk) {
      const float* xn = xb + (size_t)(ch + 1) * (kChunk * 3) + xoff;
      x0 = xn[0];
      x1 = xn[1];
      x2 = xn[2];
    }

#pragma unroll 8
    for (int t = 0; t < kChunk; ++t) {
      // input-side preactivation, pre-scaled by smul (off critical path)
      const float ctv = rl_f(ct, t);
      const float xg = fmaf(ctv, wih, bsum);

      float pre;
#if USE_FDOT2
      // f32 head for h0,h1 (keeps chain depth at 6), packed f16 for h2..h9.
      const float h0 = rl_f(h, 0), h1 = rl_f(h, 4);
      // pack (h_{2j}, h_{2j+1}) in even-hid quads: lane i <- lane i+4
      const float hnb = dpp_f<0x104>(h);  // row_shl:4 == shfl_down 4
      const half2v hpk = pkrtz(h, hnb);
      const half2v p23 = rl_h2(hpk, 8);
      const half2v p45 = rl_h2(hpk, 16);
      const half2v p67 = rl_h2(hpk, 24);
      const half2v p89 = rl_h2(hpk, 32);
      float pA = fmaf(h0, w0s, xg);
      pA = fmaf(h1, w1s, pA);
      pA = __builtin_amdgcn_fdot2(p23, wp1, pA, false);
      float pB = __builtin_amdgcn_fdot2(p45, wp2, 0.0f, false);
      pB = __builtin_amdgcn_fdot2(p67, wp3, pB, false);
      const float pC = __builtin_amdgcn_fdot2(p89, wp4, 0.0f, false);
      pre = (pA + pC) + pB;
#else
      const float h0 = rl_f(h, 0), h1 = rl_f(h, 4), h2 = rl_f(h, 8);
      const float h3 = rl_f(h, 12), h4 = rl_f(h, 16), h5 = rl_f(h, 20);
      const float h6 = rl_f(h, 24), h7 = rl_f(h, 28), h8 = rl_f(h, 32);
      const float h9 = rl_f(h, 36);
      float pA = fmaf(h0, w0s, xg);
      pA = fmaf(h1, w1s, pA);
      pA = fmaf(h2, w2s, pA);
      float pB = h3 * w3s;
      pB = fmaf(h4, w4s, pB);
      pB = fmaf(h5, w5s, pB);
      float pC = h6 * w6s;
      pC = fmaf(h7, w7s, pC);
      float pD = h8 * w8s;
      pD = fmaf(h9, w9s, pD);
      pre = (pA + pB) + (pC + pD);
#endif

      // unified activation: a = sigmoid(pre) for i/f/o, sigmoid(2*pre) for g
      const float a = fast_rcp(1.0f + fast_exp2(pre));

      // gather the quad's i,f,g,o (every lane, redundant across the quad)
      const float iv = dpp_f<0x00>(a);
      const float fv = dpp_f<0x55>(a);
      const float gv = dpp_f<0xAA>(a);  // sigma(2g); tanh(g) = 2*gv - 1
      const float ov = dpp_f<0xFF>(a);
      const float ov2 = ov + ov;  // off-path

      // cs = f*cs + C2*i + C4*i*g   (pre-scaled cell state)
      const float ti = iv * C2;
      const float pig = iv * gv;
      const float csp = fmaf(fv, cs, ti);     // parallel with pig
      cs = fmaf(pig, C4, csp);

      // h = o * tanh(c) = 2*o*sigma(2c) - o = fma(s2, 2o, -o)
      const float s2 = fast_rcp(1.0f + fast_exp2(cs));
      h = fmaf(s2, ov2, -ov);
    }
  }

  // epilogue: out[b][m] = sum_k h[k]*mlp_w[m][k] + mlp_b[m], m = 0..2
  if (lane < 3) {
    const float* mw = mlp_w + lane * kHid;
    float acc = mlp_b[lane];
    acc = fmaf(rl_f(h, 0), mw[0], acc);
    acc = fmaf(rl_f(h, 4), mw[1], acc);
    acc = fmaf(rl_f(h, 8), mw[2], acc);
    acc = fmaf(rl_f(h, 12), mw[3], acc);
    acc = fmaf(rl_f(h, 16), mw[4], acc);
    acc = fmaf(rl_f(h, 20), mw[5], acc);
    acc = fmaf(rl_f(h, 24), mw[6], acc);
    acc = fmaf(rl_f(h, 28), mw[7], acc);
    acc = fmaf(rl_f(h, 32), mw[8], acc);
    acc = fmaf(rl_f(h, 36), mw[9], acc);
    out[b * 3 + lane] = acc;
  }
}

extern "C" void kernel_launch(void* const* d_in, const int* in_sizes, int n_in,
                              void* d_out, int out_size, void* d_ws, size_t ws_size,
                              hipStream_t stream) {
  const float* x = (const float*)d_in[0];
  const float* conv_w = (const float*)d_in[1];
  const float* conv_b = (const float*)d_in[2];
  const float* w_ih = (const float*)d_in[3];
  const float* w_hh = (const float*)d_in[4];
  const float* b_ih = (const float*)d_in[5];
  const float* b_hh = (const float*)d_in[6];
  const float* mlp_w = (const float*)d_in[7];
  const float* mlp_b = (const float*)d_in[8];
  float* out = (float*)d_out;

  // 32 blocks x 1024 threads = 512 waves total, 16 waves/block = 4 waves per
  // SIMD on 32 CUs. Co-resident waves fill each other's hazard/stall issue
  // slots (SMT), which round-4 showed cannot be filled from within one wave.
  dim3 grid(kB / kWavesPerBlock), block(kWavesPerBlock * 64);
  hipLaunchKernelGGL(lstm_fused, grid, block, 0, stream, x, conv_w, conv_b,
                     w_ih, w_hh, b_ih, b_hh, mlp_w, mlp_b, out);
}

// Round 6
// 832.473 us; speedup vs baseline: 2.7853x; 2.7853x over previous
//
#include <hip/hip_runtime.h>

// Net_23484881175023: conv1d(k=3,stride=3) -> LSTM(input=1, hidden=10, T=8192) -> Linear(10,3)
// B=512, L=24576, Lp=8192.
//
// Model (R3/R4/R5 triangulation): per-step SIMD occupancy ~163 cyc is
// invariant; wall 215 = 163 busy + ~50 stall at 1 wave/SIMD. >1 batch per
// SIMD always loses (R4, R5). Only lever: cut busy cycles. ~34 instrs at
// 4.8 cyc avg -> non-full-rate ops dominate; prime suspects are the 4
// transcendentals (2 exp2 + 2 rcp).
//
// Round-6 experiment: replace BOTH v_rcp_f32 with bit-trick + 2 Newton
// iterations (pure full-rate VALU), and fully pack the h-dot (5 packed
// readlanes + 5 fdot2, no f32 head). Cell exp2 arg clamped (fmin 126) since
// Newton, unlike v_rcp, NaNs on inf input.
//
// Lane layout: lane = hid*4 + gate (40 active); i,f,g,o of hidden unit h in
// quad {4h..4h+3}; h, cs quad-uniform. smul (-log2e / -2log2e for g) folded
// into weights; cs = -2*log2e*c tracked pre-scaled.

#define DEV __device__ __forceinline__

typedef _Float16 half2v __attribute__((ext_vector_type(2)));

DEV float rl_f(float v, int lane) {
  return __int_as_float(__builtin_amdgcn_readlane(__float_as_int(v), lane));
}

DEV half2v rl_h2(half2v v, int lane) {
  int i = __builtin_amdgcn_readlane(__builtin_bit_cast(int, v), lane);
  return __builtin_bit_cast(half2v, i);
}

DEV half2v pkrtz(float a, float b) {
  return __builtin_bit_cast(half2v, __builtin_amdgcn_cvt_pkrtz(a, b));
}

template <int CTRL>
DEV float dpp_f(float v) {
#if __has_builtin(__builtin_amdgcn_mov_dpp)
  return __int_as_float(__builtin_amdgcn_mov_dpp(__float_as_int(v), CTRL, 0xF, 0xF, true));
#else
  return __int_as_float(__builtin_amdgcn_update_dpp(0, __float_as_int(v), CTRL, 0xF, 0xF, true));
#endif
}

DEV float fast_exp2(float x) {
#if __has_builtin(__builtin_amdgcn_exp2f)
  return __builtin_amdgcn_exp2f(x);
#else
  return __exp2f(x);
#endif
}

// 1/w via bit-trick seed + 2 Newton steps: full-rate VALU only (no v_rcp).
// Seed rel-err <= ~3.4% over all normal w -> after 2 NR: ~1e-5 rel.
// Requires w finite positive (guaranteed by callers).
DEV float rcp_nr(float w) {
  float y = __int_as_float(0x7EF311C3 - __float_as_int(w));
  y = y * fmaf(-w, y, 2.0f);
  y = y * fmaf(-w, y, 2.0f);
  return y;
}

#if __has_builtin(__builtin_amdgcn_fdot2)
#define USE_FDOT2 1
#else
#define USE_FDOT2 0
#endif

constexpr int kB = 512;
constexpr int kL = 24576;
constexpr int kLp = 8192;      // kL / 3
constexpr int kHid = 10;
constexpr int kChunk = 64;     // timesteps per chunk (one ct per lane)
constexpr int kNChunk = kLp / kChunk;  // 128

__global__ __launch_bounds__(256, 1) void lstm_fused(
    const float* __restrict__ x,       // (B, L, 1)
    const float* __restrict__ conv_w,  // (1,1,3)
    const float* __restrict__ conv_b,  // (1,)
    const float* __restrict__ w_ih,    // (40,1)
    const float* __restrict__ w_hh,    // (40,10)
    const float* __restrict__ b_ih,    // (40,)
    const float* __restrict__ b_hh,    // (40,)
    const float* __restrict__ mlp_w,   // (3,10)
    const float* __restrict__ mlp_b,   // (3,)
    float* __restrict__ out) {         // (B,3)
  const int lane = threadIdx.x & 63;
  const int wave = threadIdx.x >> 6;
  const int b = blockIdx.x * 4 + wave;

  const int hid = lane >> 2;   // 0..9 for active lanes
  const int gt = lane & 3;     // 0:i 1:f 2:g 3:o (torch gate order)
  const bool active = (lane < 40);
  const int r = active ? (gt * kHid + hid) : 0;  // row in the 4H-stacked weights

  // uniform conv params (scalar loads)
  const float cw0 = conv_w[0], cw1 = conv_w[1], cw2 = conv_w[2];
  const float cbv = conv_b[0];

  constexpr float kL2E = 1.4426950408889634f;  // log2(e)
  // gate g uses sigmoid(2x) (tanh folding); i/f/o use sigmoid(x).
  // Fold the exp2 scale into the weights so the dot feeds exp2 directly.
  const float smul = (gt == 2) ? (-2.0f * kL2E) : (-kL2E);

  const float wih = w_ih[r] * smul;
  const float bsum = (b_ih[r] + b_hh[r]) * smul;
  const float* wr = w_hh + r * kHid;
  const float w0s = wr[0] * smul, w1s = wr[1] * smul;
  const float w2s = wr[2] * smul, w3s = wr[3] * smul, w4s = wr[4] * smul;
  const float w5s = wr[5] * smul, w6s = wr[6] * smul, w7s = wr[7] * smul;
  const float w8s = wr[8] * smul, w9s = wr[9] * smul;

#if USE_FDOT2
  const half2v wp0 = pkrtz(w0s, w1s);
  const half2v wp1 = pkrtz(w2s, w3s);
  const half2v wp2 = pkrtz(w4s, w5s);
  const half2v wp3 = pkrtz(w6s, w7s);
  const half2v wp4 = pkrtz(w8s, w9s);
#endif

  // cell-update constants (cs = -2*log2e * c is the tracked state):
  //   cs_new = f*cs + C2*i + C4*i*g,  C4 = -4*log2e, C2 = 2*log2e
  const float C4 = -4.0f * kL2E;
  const float C2 = 2.0f * kL2E;

  const float* xb = x + (size_t)b * kL;
  const int xoff = lane * 3;

  // prefetch chunk 0's x values
  float x0 = xb[xoff + 0];
  float x1 = xb[xoff + 1];
  float x2 = xb[xoff + 2];

  float h = 0.0f;   // lane's quad value of h[hid]
  float cs = 0.0f;  // -2*log2e * c[hid]

  for (int ch = 0; ch < kNChunk; ++ch) {
    // conv output for timestep (ch*64 + lane), all 64 lanes
    float ct = fmaf(x2, cw2, fmaf(x1, cw1, fmaf(x0, cw0, cbv)));
    ct = fmaxf(ct, 0.0f);

    // prefetch next chunk (consumed after the 64-step inner loop)
    if (ch + 1 < kNChunk) {
      const float* xn = xb + (size_t)(ch + 1) * (kChunk * 3) + xoff;
      x0 = xn[0];
      x1 = xn[1];
      x2 = xn[2];
    }

#pragma unroll 8
    for (int t = 0; t < kChunk; ++t) {
      // input-side preactivation, pre-scaled by smul (off critical path)
      const float ctv = rl_f(ct, t);
      const float xg = fmaf(ctv, wih, bsum);

      float pre;
#if USE_FDOT2
      // fully packed dot: 1 dpp + 1 cvt + 5 packed readlanes + 5 fdot2
      const float hnb = dpp_f<0x104>(h);  // row_shl:4 (lane i <- i+4)
      const half2v hpk = pkrtz(h, hnb);   // (h_{2j}, h_{2j+1}) in even-hid quads
      const half2v p01 = rl_h2(hpk, 0);
      const half2v p23 = rl_h2(hpk, 8);
      const half2v p45 = rl_h2(hpk, 16);
      const half2v p67 = rl_h2(hpk, 24);
      const half2v p89 = rl_h2(hpk, 32);
      float pA = __builtin_amdgcn_fdot2(p01, wp0, xg, false);
      pA = __builtin_amdgcn_fdot2(p23, wp1, pA, false);
      float pB = __builtin_amdgcn_fdot2(p45, wp2, 0.0f, false);
      pB = __builtin_amdgcn_fdot2(p67, wp3, pB, false);
      const float pC = __builtin_amdgcn_fdot2(p89, wp4, 0.0f, false);
      pre = (pA + pB) + pC;
#else
      const float h0 = rl_f(h, 0), h1 = rl_f(h, 4), h2 = rl_f(h, 8);
      const float h3 = rl_f(h, 12), h4 = rl_f(h, 16), h5 = rl_f(h, 20);
      const float h6 = rl_f(h, 24), h7 = rl_f(h, 28), h8 = rl_f(h, 32);
      const float h9 = rl_f(h, 36);
      float pA = fmaf(h0, w0s, xg);
      pA = fmaf(h1, w1s, pA);
      pA = fmaf(h2, w2s, pA);
      float pB = h3 * w3s;
      pB = fmaf(h4, w4s, pB);
      pB = fmaf(h5, w5s, pB);
      float pC = h6 * w6s;
      pC = fmaf(h7, w7s, pC);
      float pD = h8 * w8s;
      pD = fmaf(h9, w9s, pD);
      pre = (pA + pB) + (pC + pD);
#endif

      // unified activation: a = sigmoid(pre) for i/f/o, sigmoid(2*pre) for g.
      // |pre| <= ~9 by weight-scale arithmetic -> E in [2^-9, 2^9], w finite.
      const float a = rcp_nr(1.0f + fast_exp2(pre));

      // gather the quad's i,f,g,o (every lane, redundant across the quad)
      const float iv = dpp_f<0x00>(a);
      const float fv = dpp_f<0x55>(a);
      const float gv = dpp_f<0xAA>(a);  // sigma(2g); tanh(g) = 2*gv - 1
      const float ov = dpp_f<0xFF>(a);
      const float ov2 = ov + ov;  // off-path

      // cs = f*cs + C2*i + C4*i*g   (pre-scaled cell state)
      const float ti = iv * C2;
      const float pig = iv * gv;
      const float csp = fmaf(fv, cs, ti);     // parallel with pig
      cs = fmaf(pig, C4, csp);

      // h = o * tanh(c) = fma(sigma(2c), 2o, -o). Clamp the exp2 ARG (not the
      // state) so E can't overflow to inf (Newton NaNs on inf; v_rcp didn't).
      const float csc = fminf(cs, 126.0f);
      const float s2 = rcp_nr(1.0f + fast_exp2(csc));
      h = fmaf(s2, ov2, -ov);
    }
  }

  // epilogue: out[b][m] = sum_k h[k]*mlp_w[m][k] + mlp_b[m], m = 0..2
  if (lane < 3) {
    const float* mw = mlp_w + lane * kHid;
    float acc = mlp_b[lane];
    acc = fmaf(rl_f(h, 0), mw[0], acc);
    acc = fmaf(rl_f(h, 4), mw[1], acc);
    acc = fmaf(rl_f(h, 8), mw[2], acc);
    acc = fmaf(rl_f(h, 12), mw[3], acc);
    acc = fmaf(rl_f(h, 16), mw[4], acc);
    acc = fmaf(rl_f(h, 20), mw[5], acc);
    acc = fmaf(rl_f(h, 24), mw[6], acc);
    acc = fmaf(rl_f(h, 28), mw[7], acc);
    acc = fmaf(rl_f(h, 32), mw[8], acc);
    acc = fmaf(rl_f(h, 36), mw[9], acc);
    out[b * 3 + lane] = acc;
  }
}

extern "C" void kernel_launch(void* const* d_in, const int* in_sizes, int n_in,
                              void* d_out, int out_size, void* d_ws, size_t ws_size,
                              hipStream_t stream) {
  const float* x = (const float*)d_in[0];
  const float* conv_w = (const float*)d_in[1];
  const float* conv_b = (const float*)d_in[2];
  const float* w_ih = (const float*)d_in[3];
  const float* w_hh = (const float*)d_in[4];
  const float* b_ih = (const float*)d_in[5];
  const float* b_hh = (const float*)d_in[6];
  const float* mlp_w = (const float*)d_in[7];
  const float* mlp_b = (const float*)d_in[8];
  float* out = (float*)d_out;

  // 128 blocks x 256 threads = 512 waves; one wave per batch element,
  // 1 wave per SIMD chip-wide (R3/R5 established this is the only shape
  // where wall time ~= single-chain time).
  dim3 grid(kB / 4), block(256);
  hipLaunchKernelGGL(lstm_fused, grid, block, 0, stream, x, conv_w, conv_b,
                     w_ih, w_hh, b_ih, b_hh, mlp_w, mlp_b, out);
}

// Round 7
// 752.521 us; speedup vs baseline: 3.0812x; 1.1062x over previous
//
#include <hip/hip_runtime.h>

// Net_23484881175023: conv1d(k=3,stride=3) -> LSTM(input=1, hidden=10, T=8192) -> Linear(10,3)
// B=512, L=24576, Lp=8192.
//
// Model (R3-R6): busy/step ~163 cyc (invariant), wall ~215 at 1 wave/SIMD;
// marginal full-rate instr ~2.3 cyc; trans issue cheap (R6 Newton regressed);
// remaining overhead sits on the 12 cross-lane ops (readlane SGPR hazards,
// DPP waits). TLP (R5) and multi-batch ILP (R4) are closed: >1 batch/SIMD
// multiplies wall.
//
// Round-7 (all exact-arithmetic):
//  - revert Newton -> v_rcp (R6 falsified trans-issue theory); keep R6's
//    fully-packed f16 dot (5 packed readlanes + 5 fdot2).
//  - ct via per-wave double-buffered LDS instead of v_readlane: broadcast
//    ds_read_b32 with immediate offset, off the VALU/SGPR hazard path,
//    hoistable by the scheduler. Conv for chunk ch+1 computed at the END of
//    chunk ch's body (x loads issued at the top -> latency hidden by the
//    64-step inner loop).
//  - unroll 16: longer window to overlap readlane->fdot2 hazards with the
//    next steps' off-chain work.

#define DEV __device__ __forceinline__

typedef _Float16 half2v __attribute__((ext_vector_type(2)));

DEV float rl_f(float v, int lane) {
  return __int_as_float(__builtin_amdgcn_readlane(__float_as_int(v), lane));
}

DEV half2v rl_h2(half2v v, int lane) {
  int i = __builtin_amdgcn_readlane(__builtin_bit_cast(int, v), lane);
  return __builtin_bit_cast(half2v, i);
}

DEV half2v pkrtz(float a, float b) {
  return __builtin_bit_cast(half2v, __builtin_amdgcn_cvt_pkrtz(a, b));
}

template <int CTRL>
DEV float dpp_f(float v) {
#if __has_builtin(__builtin_amdgcn_mov_dpp)
  return __int_as_float(__builtin_amdgcn_mov_dpp(__float_as_int(v), CTRL, 0xF, 0xF, true));
#else
  return __int_as_float(__builtin_amdgcn_update_dpp(0, __float_as_int(v), CTRL, 0xF, 0xF, true));
#endif
}

DEV float fast_exp2(float x) {
#if __has_builtin(__builtin_amdgcn_exp2f)
  return __builtin_amdgcn_exp2f(x);
#else
  return __exp2f(x);
#endif
}

DEV float fast_rcp(float x) { return __builtin_amdgcn_rcpf(x); }

#if __has_builtin(__builtin_amdgcn_fdot2)
#define USE_FDOT2 1
#else
#define USE_FDOT2 0
#endif

constexpr int kB = 512;
constexpr int kL = 24576;
constexpr int kLp = 8192;      // kL / 3
constexpr int kHid = 10;
constexpr int kChunk = 64;     // timesteps per chunk (one ct per lane)
constexpr int kNChunk = kLp / kChunk;  // 128

__global__ __launch_bounds__(256, 1) void lstm_fused(
    const float* __restrict__ x,       // (B, L, 1)
    const float* __restrict__ conv_w,  // (1,1,3)
    const float* __restrict__ conv_b,  // (1,)
    const float* __restrict__ w_ih,    // (40,1)
    const float* __restrict__ w_hh,    // (40,10)
    const float* __restrict__ b_ih,    // (40,)
    const float* __restrict__ b_hh,    // (40,)
    const float* __restrict__ mlp_w,   // (3,10)
    const float* __restrict__ mlp_b,   // (3,)
    float* __restrict__ out) {         // (B,3)
  const int lane = threadIdx.x & 63;
  const int wave = threadIdx.x >> 6;
  const int b = blockIdx.x * 4 + wave;

  // per-wave double-buffered conv-output stage (broadcast reads, no conflicts)
  __shared__ float ctlds[4][2][kChunk];

  const int hid = lane >> 2;   // 0..9 for active lanes
  const int gt = lane & 3;     // 0:i 1:f 2:g 3:o (torch gate order)
  const bool active = (lane < 40);
  const int r = active ? (gt * kHid + hid) : 0;  // row in the 4H-stacked weights

  // uniform conv params (scalar loads)
  const float cw0 = conv_w[0], cw1 = conv_w[1], cw2 = conv_w[2];
  const float cbv = conv_b[0];

  constexpr float kL2E = 1.4426950408889634f;  // log2(e)
  // gate g uses sigmoid(2x) (tanh folding); i/f/o use sigmoid(x).
  // Fold the exp2 scale into the weights so the dot feeds exp2 directly.
  const float smul = (gt == 2) ? (-2.0f * kL2E) : (-kL2E);

  const float wih = w_ih[r] * smul;
  const float bsum = (b_ih[r] + b_hh[r]) * smul;
  const float* wr = w_hh + r * kHid;
  const float w0s = wr[0] * smul, w1s = wr[1] * smul;
  const float w2s = wr[2] * smul, w3s = wr[3] * smul, w4s = wr[4] * smul;
  const float w5s = wr[5] * smul, w6s = wr[6] * smul, w7s = wr[7] * smul;
  const float w8s = wr[8] * smul, w9s = wr[9] * smul;

#if USE_FDOT2
  const half2v wp0 = pkrtz(w0s, w1s);
  const half2v wp1 = pkrtz(w2s, w3s);
  const half2v wp2 = pkrtz(w4s, w5s);
  const half2v wp3 = pkrtz(w6s, w7s);
  const half2v wp4 = pkrtz(w8s, w9s);
#endif

  // cell-update constants (cs = -2*log2e * c is the tracked state):
  //   cs_new = f*cs + C2*i + C4*i*g,  C4 = -4*log2e, C2 = 2*log2e
  const float C4 = -4.0f * kL2E;
  const float C2 = 2.0f * kL2E;

  const float* xb = x + (size_t)b * kL;
  const int xoff = lane * 3;

  // chunk 0: load x, compute conv, stage to LDS buffer 0
  float x0 = xb[xoff + 0];
  float x1 = xb[xoff + 1];
  float x2 = xb[xoff + 2];
  {
    float ct0 = fmaf(x2, cw2, fmaf(x1, cw1, fmaf(x0, cw0, cbv)));
    ctlds[wave][0][lane] = fmaxf(ct0, 0.0f);
  }

  float h = 0.0f;   // lane's quad value of h[hid]
  float cs = 0.0f;  // -2*log2e * c[hid]

  for (int ch = 0; ch < kNChunk; ++ch) {
    const float* cbuf = &ctlds[wave][ch & 1][0];
    const bool have_next = (ch + 1 < kNChunk);

    // issue next chunk's x loads now; consumed after the 64-step inner loop
    if (have_next) {
      const float* xn = xb + (size_t)(ch + 1) * (kChunk * 3) + xoff;
      x0 = xn[0];
      x1 = xn[1];
      x2 = xn[2];
    }

#pragma unroll 16
    for (int t = 0; t < kChunk; ++t) {
      // conv output for this timestep: broadcast LDS read (off VALU/SGPR path)
      const float ctv = cbuf[t];
      const float xg = fmaf(ctv, wih, bsum);  // off critical path

      float pre;
#if USE_FDOT2
      // fully packed dot: 1 dpp + 1 cvt + 5 packed readlanes + 5 fdot2
      const float hnb = dpp_f<0x104>(h);  // row_shl:4 (lane i <- i+4)
      const half2v hpk = pkrtz(h, hnb);   // (h_{2j}, h_{2j+1}) in even-hid quads
      const half2v p01 = rl_h2(hpk, 0);
      const half2v p23 = rl_h2(hpk, 8);
      const half2v p45 = rl_h2(hpk, 16);
      const half2v p67 = rl_h2(hpk, 24);
      const half2v p89 = rl_h2(hpk, 32);
      float pA = __builtin_amdgcn_fdot2(p01, wp0, xg, false);
      pA = __builtin_amdgcn_fdot2(p23, wp1, pA, false);
      float pB = __builtin_amdgcn_fdot2(p45, wp2, 0.0f, false);
      pB = __builtin_amdgcn_fdot2(p67, wp3, pB, false);
      const float pC = __builtin_amdgcn_fdot2(p89, wp4, 0.0f, false);
      pre = (pA + pB) + pC;
#else
      const float h0 = rl_f(h, 0), h1 = rl_f(h, 4), h2 = rl_f(h, 8);
      const float h3 = rl_f(h, 12), h4 = rl_f(h, 16), h5 = rl_f(h, 20);
      const float h6 = rl_f(h, 24), h7 = rl_f(h, 28), h8 = rl_f(h, 32);
      const float h9 = rl_f(h, 36);
      float pA = fmaf(h0, w0s, xg);
      pA = fmaf(h1, w1s, pA);
      pA = fmaf(h2, w2s, pA);
      float pB = h3 * w3s;
      pB = fmaf(h4, w4s, pB);
      pB = fmaf(h5, w5s, pB);
      float pC = h6 * w6s;
      pC = fmaf(h7, w7s, pC);
      float pD = h8 * w8s;
      pD = fmaf(h9, w9s, pD);
      pre = (pA + pB) + (pC + pD);
#endif

      // unified activation: a = sigmoid(pre) for i/f/o, sigmoid(2*pre) for g
      const float a = fast_rcp(1.0f + fast_exp2(pre));

      // gather the quad's i,f,g,o (every lane, redundant across the quad)
      const float iv = dpp_f<0x00>(a);
      const float fv = dpp_f<0x55>(a);
      const float gv = dpp_f<0xAA>(a);  // sigma(2g); tanh(g) = 2*gv - 1
      const float ov = dpp_f<0xFF>(a);
      const float ov2 = ov + ov;  // off-path

      // cs = f*cs + C2*i + C4*i*g   (pre-scaled cell state)
      const float ti = iv * C2;
      const float pig = iv * gv;
      const float csp = fmaf(fv, cs, ti);     // parallel with pig
      cs = fmaf(pig, C4, csp);

      // h = o * tanh(c) = 2*o*sigma(2c) - o = fma(s2, 2o, -o)
      const float s2 = fast_rcp(1.0f + fast_exp2(cs));
      h = fmaf(s2, ov2, -ov);
    }

    // stage next chunk's conv outputs (x loads issued at top of this chunk)
    if (have_next) {
      float ctn = fmaf(x2, cw2, fmaf(x1, cw1, fmaf(x0, cw0, cbv)));
      ctlds[wave][(ch & 1) ^ 1][lane] = fmaxf(ctn, 0.0f);
    }
  }

  // epilogue: out[b][m] = sum_k h[k]*mlp_w[m][k] + mlp_b[m], m = 0..2
  if (lane < 3) {
    const float* mw = mlp_w + lane * kHid;
    float acc = mlp_b[lane];
    acc = fmaf(rl_f(h, 0), mw[0], acc);
    acc = fmaf(rl_f(h, 4), mw[1], acc);
    acc = fmaf(rl_f(h, 8), mw[2], acc);
    acc = fmaf(rl_f(h, 12), mw[3], acc);
    acc = fmaf(rl_f(h, 16), mw[4], acc);
    acc = fmaf(rl_f(h, 20), mw[5], acc);
    acc = fmaf(rl_f(h, 24), mw[6], acc);
    acc = fmaf(rl_f(h, 28), mw[7], acc);
    acc = fmaf(rl_f(h, 32), mw[8], acc);
    acc = fmaf(rl_f(h, 36), mw[9], acc);
    out[b * 3 + lane] = acc;
  }
}

extern "C" void kernel_launch(void* const* d_in, const int* in_sizes, int n_in,
                              void* d_out, int out_size, void* d_ws, size_t ws_size,
                              hipStream_t stream) {
  const float* x = (const float*)d_in[0];
  const float* conv_w = (const float*)d_in[1];
  const float* conv_b = (const float*)d_in[2];
  const float* w_ih = (const float*)d_in[3];
  const float* w_hh = (const float*)d_in[4];
  const float* b_ih = (const float*)d_in[5];
  const float* b_hh = (const float*)d_in[6];
  const float* mlp_w = (const float*)d_in[7];
  const float* mlp_b = (const float*)d_in[8];
  float* out = (float*)d_out;

  // 128 blocks x 256 threads = 512 waves; one wave per batch element,
  // 1 wave per SIMD chip-wide (R3/R4/R5: the only shape where wall ~= chain).
  dim3 grid(kB / 4), block(256);
  hipLaunchKernelGGL(lstm_fused, grid, block, 0, stream, x, conv_w, conv_b,
                     w_ih, w_hh, b_ih, b_hh, mlp_w, mlp_b, out);
}

// Round 8
// 739.118 us; speedup vs baseline: 3.1370x; 1.0181x over previous
//
#include <hip/hip_runtime.h>

// Net_23484881175023: conv1d(k=3,stride=3) -> LSTM(input=1, hidden=10, T=8192) -> Linear(10,3)
// B=512, L=24576, Lp=8192.
//
// Model (R3-R7): single-wave in-order chain is the binding constraint
// (wall ~207 cyc/step, busy ~145). TLP/multi-batch ILP closed (R4/R5:
// per-wave latency IS total time since B == #waves). Cross-lane ops cost
// ~6 busy cyc each (R7: -1 readlane+2 VALU = -18 busy). Levers left: trim
// on-chain cross-lane ops.
//
// Round-8: gate gathers 4 dpps -> 3. cs/h only need to be VALID AT gt=0
// lanes (the h-pack reads lanes {0,8,..,36} only):
//   - i = own a at gt0 (iv broadcast dpp DELETED; ti = a*C2)
//   - i*g at gt0 via ONE quad-rotate-2 dpp + mul (m = a * rot2(a))
//   - f,o quad broadcasts unchanged (2 dpps)
// gt!=0 lanes carry bounded garbage (sigmoid products, |f|<1 contraction,
// v_rcp(inf)=0) -> no NaN/inf propagation; exact arithmetic unchanged at
// gt0 lanes.
//
// Retained: LDS-staged conv outputs (double-buffered, broadcast ds_read),
// fully-packed f16 dot (dpp row_shl:4 + pkrtz + 5 packed readlane + 5 fdot2),
// smul folded into weights, pre-scaled cell state cs = -2*log2e*c, unroll 16,
// 128 blocks x 256 threads (1 wave/SIMD).

#define DEV __device__ __forceinline__

typedef _Float16 half2v __attribute__((ext_vector_type(2)));

DEV float rl_f(float v, int lane) {
  return __int_as_float(__builtin_amdgcn_readlane(__float_as_int(v), lane));
}

DEV half2v rl_h2(half2v v, int lane) {
  int i = __builtin_amdgcn_readlane(__builtin_bit_cast(int, v), lane);
  return __builtin_bit_cast(half2v, i);
}

DEV half2v pkrtz(float a, float b) {
  return __builtin_bit_cast(half2v, __builtin_amdgcn_cvt_pkrtz(a, b));
}

template <int CTRL>
DEV float dpp_f(float v) {
#if __has_builtin(__builtin_amdgcn_mov_dpp)
  return __int_as_float(__builtin_amdgcn_mov_dpp(__float_as_int(v), CTRL, 0xF, 0xF, true));
#else
  return __int_as_float(__builtin_amdgcn_update_dpp(0, __float_as_int(v), CTRL, 0xF, 0xF, true));
#endif
}

DEV float fast_exp2(float x) {
#if __has_builtin(__builtin_amdgcn_exp2f)
  return __builtin_amdgcn_exp2f(x);
#else
  return __exp2f(x);
#endif
}

DEV float fast_rcp(float x) { return __builtin_amdgcn_rcpf(x); }

#if __has_builtin(__builtin_amdgcn_fdot2)
#define USE_FDOT2 1
#else
#define USE_FDOT2 0
#endif

constexpr int kB = 512;
constexpr int kL = 24576;
constexpr int kLp = 8192;      // kL / 3
constexpr int kHid = 10;
constexpr int kChunk = 64;     // timesteps per chunk (one ct per lane)
constexpr int kNChunk = kLp / kChunk;  // 128

__global__ __launch_bounds__(256, 1) void lstm_fused(
    const float* __restrict__ x,       // (B, L, 1)
    const float* __restrict__ conv_w,  // (1,1,3)
    const float* __restrict__ conv_b,  // (1,)
    const float* __restrict__ w_ih,    // (40,1)
    const float* __restrict__ w_hh,    // (40,10)
    const float* __restrict__ b_ih,    // (40,)
    const float* __restrict__ b_hh,    // (40,)
    const float* __restrict__ mlp_w,   // (3,10)
    const float* __restrict__ mlp_b,   // (3,)
    float* __restrict__ out) {         // (B,3)
  const int lane = threadIdx.x & 63;
  const int wave = threadIdx.x >> 6;
  const int b = blockIdx.x * 4 + wave;

  // per-wave double-buffered conv-output stage (broadcast reads, no conflicts)
  __shared__ float ctlds[4][2][kChunk];

  const int hid = lane >> 2;   // 0..9 for active lanes
  const int gt = lane & 3;     // 0:i 1:f 2:g 3:o (torch gate order)
  const bool active = (lane < 40);
  const int r = active ? (gt * kHid + hid) : 0;  // row in the 4H-stacked weights

  // uniform conv params (scalar loads)
  const float cw0 = conv_w[0], cw1 = conv_w[1], cw2 = conv_w[2];
  const float cbv = conv_b[0];

  constexpr float kL2E = 1.4426950408889634f;  // log2(e)
  // gate g uses sigmoid(2x) (tanh folding); i/f/o use sigmoid(x).
  // Fold the exp2 scale into the weights so the dot feeds exp2 directly.
  const float smul = (gt == 2) ? (-2.0f * kL2E) : (-kL2E);

  const float wih = w_ih[r] * smul;
  const float bsum = (b_ih[r] + b_hh[r]) * smul;
  const float* wr = w_hh + r * kHid;
  const float w0s = wr[0] * smul, w1s = wr[1] * smul;
  const float w2s = wr[2] * smul, w3s = wr[3] * smul, w4s = wr[4] * smul;
  const float w5s = wr[5] * smul, w6s = wr[6] * smul, w7s = wr[7] * smul;
  const float w8s = wr[8] * smul, w9s = wr[9] * smul;

#if USE_FDOT2
  const half2v wp0 = pkrtz(w0s, w1s);
  const half2v wp1 = pkrtz(w2s, w3s);
  const half2v wp2 = pkrtz(w4s, w5s);
  const half2v wp3 = pkrtz(w6s, w7s);
  const half2v wp4 = pkrtz(w8s, w9s);
#endif

  // cell-update constants (cs = -2*log2e * c is the tracked state):
  //   cs_new = f*cs + C2*i + C4*i*g,  C4 = -4*log2e, C2 = 2*log2e
  const float C4 = -4.0f * kL2E;
  const float C2 = 2.0f * kL2E;

  const float* xb = x + (size_t)b * kL;
  const int xoff = lane * 3;

  // chunk 0: load x, compute conv, stage to LDS buffer 0
  float x0 = xb[xoff + 0];
  float x1 = xb[xoff + 1];
  float x2 = xb[xoff + 2];
  {
    float ct0 = fmaf(x2, cw2, fmaf(x1, cw1, fmaf(x0, cw0, cbv)));
    ctlds[wave][0][lane] = fmaxf(ct0, 0.0f);
  }

  float h = 0.0f;   // h[hid] (valid at gt=0 lanes)
  float cs = 0.0f;  // -2*log2e * c[hid] (valid at gt=0 lanes)

  for (int ch = 0; ch < kNChunk; ++ch) {
    const float* cbuf = &ctlds[wave][ch & 1][0];
    const bool have_next = (ch + 1 < kNChunk);

    // issue next chunk's x loads now; consumed after the 64-step inner loop
    if (have_next) {
      const float* xn = xb + (size_t)(ch + 1) * (kChunk * 3) + xoff;
      x0 = xn[0];
      x1 = xn[1];
      x2 = xn[2];
    }

#pragma unroll 16
    for (int t = 0; t < kChunk; ++t) {
      // conv output for this timestep: broadcast LDS read (off VALU/SGPR path)
      const float ctv = cbuf[t];
      const float xg = fmaf(ctv, wih, bsum);  // off critical path

      float pre;
#if USE_FDOT2
      // fully packed dot: 1 dpp + 1 cvt + 5 packed readlanes + 5 fdot2.
      // Sources {0,8,16,24,32} and row_shl:4 sources {4..36} are all gt=0.
      const float hnb = dpp_f<0x104>(h);  // row_shl:4 (lane i <- i+4)
      const half2v hpk = pkrtz(h, hnb);   // (h_{2j}, h_{2j+1}) in even-hid quads
      const half2v p01 = rl_h2(hpk, 0);
      const half2v p23 = rl_h2(hpk, 8);
      const half2v p45 = rl_h2(hpk, 16);
      const half2v p67 = rl_h2(hpk, 24);
      const half2v p89 = rl_h2(hpk, 32);
      float pA = __builtin_amdgcn_fdot2(p01, wp0, xg, false);
      pA = __builtin_amdgcn_fdot2(p23, wp1, pA, false);
      float pB = __builtin_amdgcn_fdot2(p45, wp2, 0.0f, false);
      pB = __builtin_amdgcn_fdot2(p67, wp3, pB, false);
      const float pC = __builtin_amdgcn_fdot2(p89, wp4, 0.0f, false);
      pre = (pA + pB) + pC;
#else
      const float h0 = rl_f(h, 0), h1 = rl_f(h, 4), h2 = rl_f(h, 8);
      const float h3 = rl_f(h, 12), h4 = rl_f(h, 16), h5 = rl_f(h, 20);
      const float h6 = rl_f(h, 24), h7 = rl_f(h, 28), h8 = rl_f(h, 32);
      const float h9 = rl_f(h, 36);
      float pA = fmaf(h0, w0s, xg);
      pA = fmaf(h1, w1s, pA);
      pA = fmaf(h2, w2s, pA);
      float pB = h3 * w3s;
      pB = fmaf(h4, w4s, pB);
      pB = fmaf(h5, w5s, pB);
      float pC = h6 * w6s;
      pC = fmaf(h7, w7s, pC);
      float pD = h8 * w8s;
      pD = fmaf(h9, w9s, pD);
      pre = (pA + pB) + (pC + pD);
#endif

      // unified activation: a = sigmoid(pre) for i/f/o, sigmoid(2*pre) for g
      const float a = fast_rcp(1.0f + fast_exp2(pre));

      // 3-dpp cell/h block (cs,h valid at gt=0 lanes only):
      //   lane 4h holds a = i; rot2 brings g; f,o broadcast.
      const float ar2 = dpp_f<0x4E>(a);   // quad rotate-2: gt0 lane gets g
      const float fb = dpp_f<0x55>(a);    // f broadcast
      const float ob = dpp_f<0xFF>(a);    // o broadcast
      const float m = a * ar2;            // i*g at gt0
      const float ti = a * C2;            // C2*i at gt0 (off-path)
      const float ov2 = ob + ob;          // off-path

      // cs = f*cs + C2*i + C4*i*g   (pre-scaled cell state)
      const float csp = fmaf(fb, cs, ti);  // parallel with m
      cs = fmaf(m, C4, csp);

      // h = o * tanh(c) = 2*o*sigma(2c) - o = fma(s2, 2o, -o)
      const float s2 = fast_rcp(1.0f + fast_exp2(cs));
      h = fmaf(s2, ov2, -ob);
    }

    // stage next chunk's conv outputs (x loads issued at top of this chunk)
    if (have_next) {
      float ctn = fmaf(x2, cw2, fmaf(x1, cw1, fmaf(x0, cw0, cbv)));
      ctlds[wave][(ch & 1) ^ 1][lane] = fmaxf(ctn, 0.0f);
    }
  }

  // epilogue: out[b][m] = sum_k h[k]*mlp_w[m][k] + mlp_b[m], m = 0..2
  // (h read from gt=0 lanes {0,4,...,36} — valid by construction)
  if (lane < 3) {
    const float* mw = mlp_w + lane * kHid;
    float acc = mlp_b[lane];
    acc = fmaf(rl_f(h, 0), mw[0], acc);
    acc = fmaf(rl_f(h, 4), mw[1], acc);
    acc = fmaf(rl_f(h, 8), mw[2], acc);
    acc = fmaf(rl_f(h, 12), mw[3], acc);
    acc = fmaf(rl_f(h, 16), mw[4], acc);
    acc = fmaf(rl_f(h, 20), mw[5], acc);
    acc = fmaf(rl_f(h, 24), mw[6], acc);
    acc = fmaf(rl_f(h, 28), mw[7], acc);
    acc = fmaf(rl_f(h, 32), mw[8], acc);
    acc = fmaf(rl_f(h, 36), mw[9], acc);
    out[b * 3 + lane] = acc;
  }
}

extern "C" void kernel_launch(void* const* d_in, const int* in_sizes, int n_in,
                              void* d_out, int out_size, void* d_ws, size_t ws_size,
                              hipStream_t stream) {
  const float* x = (const float*)d_in[0];
  const float* conv_w = (const float*)d_in[1];
  const float* conv_b = (const float*)d_in[2];
  const float* w_ih = (const float*)d_in[3];
  const float* w_hh = (const float*)d_in[4];
  const float* b_ih = (const float*)d_in[5];
  const float* b_hh = (const float*)d_in[6];
  const float* mlp_w = (const float*)d_in[7];
  const float* mlp_b = (const float*)d_in[8];
  float* out = (float*)d_out;

  // 128 blocks x 256 threads = 512 waves; one wave per batch element,
  // 1 wave per SIMD chip-wide (R3/R4/R5: the only shape where wall ~= chain).
  dim3 grid(kB / 4), block(256);
  hipLaunchKernelGGL(lstm_fused, grid, block, 0, stream, x, conv_w, conv_b,
                     w_ih, w_hh, b_ih, b_hh, mlp_w, mlp_b, out);
}